// Round 3
// baseline (1257.131 us; speedup 1.0000x reference)
//
#include <hip/hip_runtime.h>
#include <math.h>

// Problem constants (fixed by the reference)
#define BATCH 2
#define T_LEN 2048
#define D_DIM 1024
#define KSEL  15
#define HIDN  64

__device__ __forceinline__ float geluf(float x) {
  return 0.5f * x * (1.0f + erff(x * 0.70710678118654752440f));
}

// ---------------------------------------------------------------------------
// f32 GEMM, 128x128 tile, BK=16, 256 threads, 8x8 per thread. Smooth path only.
// ---------------------------------------------------------------------------
__global__ void __launch_bounds__(256) gemm128(const float* __restrict__ A,
                                               const float* __restrict__ B,
                                               float* __restrict__ C,
                                               int M, int N, int K, float alpha)
{
  const int m0 = blockIdx.y << 7, n0 = blockIdx.x << 7;
  const int tid = threadIdx.x;
  const int tx = tid & 15, ty = tid >> 4;

  __shared__ float As[16][128];
  __shared__ float Bs[16][132];

  float acc[8][8];
#pragma unroll
  for (int i = 0; i < 8; ++i)
#pragma unroll
    for (int j = 0; j < 8; ++j) acc[i][j] = 0.f;

  for (int k0 = 0; k0 < K; k0 += 16) {
#pragma unroll
    for (int rep = 0; rep < 2; ++rep) {
      int q = tid + (rep << 8);
      int m = q >> 2, kq = (q & 3) << 2;
      float4 a = *(const float4*)(A + (size_t)(m0 + m) * K + k0 + kq);
      As[kq + 0][m] = a.x; As[kq + 1][m] = a.y; As[kq + 2][m] = a.z; As[kq + 3][m] = a.w;
    }
#pragma unroll
    for (int rep = 0; rep < 2; ++rep) {
      int q = tid + (rep << 8);
      int kk = q >> 5, n4 = q & 31;
      *(float4*)&Bs[kk][n4 << 2] =
          *(const float4*)(B + (size_t)(k0 + kk) * N + n0 + (n4 << 2));
    }
    __syncthreads();
#pragma unroll
    for (int kk = 0; kk < 16; ++kk) {
      float4 a0 = *(const float4*)&As[kk][ty << 3];
      float4 a1 = *(const float4*)&As[kk][(ty << 3) + 4];
      float4 b0 = *(const float4*)&Bs[kk][tx << 3];
      float4 b1 = *(const float4*)&Bs[kk][(tx << 3) + 4];
      float av[8] = {a0.x, a0.y, a0.z, a0.w, a1.x, a1.y, a1.z, a1.w};
      float bv[8] = {b0.x, b0.y, b0.z, b0.w, b1.x, b1.y, b1.z, b1.w};
#pragma unroll
      for (int i = 0; i < 8; ++i)
#pragma unroll
        for (int j = 0; j < 8; ++j)
          acc[i][j] = fmaf(av[i], bv[j], acc[i][j]);
    }
    __syncthreads();
  }
#pragma unroll
  for (int i = 0; i < 8; ++i) {
    size_t coff = (size_t)(m0 + (ty << 3) + i) * N + n0 + (tx << 3);
    float4 o0 = make_float4(acc[i][0] * alpha, acc[i][1] * alpha, acc[i][2] * alpha, acc[i][3] * alpha);
    float4 o1 = make_float4(acc[i][4] * alpha, acc[i][5] * alpha, acc[i][6] * alpha, acc[i][7] * alpha);
    *(float4*)(C + coff) = o0;
    *(float4*)(C + coff + 4) = o1;
  }
}

// ---------------------------------------------------------------------------
// f64-ACCUMULATE GEMM (f32 in / f32 out). 64x64 tile, BK=16, 4x4 per thread.
// Selection-critical path.
// ---------------------------------------------------------------------------
template<bool BT, bool CAUSAL>
__global__ void __launch_bounds__(256) gemm64d(const float* __restrict__ A,
                                               const float* __restrict__ B,
                                               float* __restrict__ C,
                                               int M, int N, int K, double alpha)
{
  if (CAUSAL && blockIdx.x > blockIdx.y) return;
  const int m0 = blockIdx.y << 6, n0 = blockIdx.x << 6;
  const int tid = threadIdx.x;
  const int tx = tid & 15, ty = tid >> 4;

  __shared__ float As[16][64];
  __shared__ float Bs[16][68];

  double acc[4][4];
#pragma unroll
  for (int i = 0; i < 4; ++i)
#pragma unroll
    for (int j = 0; j < 4; ++j) acc[i][j] = 0.0;

  for (int k0 = 0; k0 < K; k0 += 16) {
    {
      int m = tid >> 2, kq = (tid & 3) << 2;
      float4 a = *(const float4*)(A + (size_t)(m0 + m) * K + k0 + kq);
      As[kq + 0][m] = a.x; As[kq + 1][m] = a.y; As[kq + 2][m] = a.z; As[kq + 3][m] = a.w;
    }
    if (!BT) {
      int kk = tid >> 4, n4 = tid & 15;
      *(float4*)&Bs[kk][n4 << 2] =
          *(const float4*)(B + (size_t)(k0 + kk) * N + n0 + (n4 << 2));
    } else {
      int n = tid >> 2, kq = (tid & 3) << 2;
      float4 b = *(const float4*)(B + (size_t)(n0 + n) * K + k0 + kq);
      Bs[kq + 0][n] = b.x; Bs[kq + 1][n] = b.y; Bs[kq + 2][n] = b.z; Bs[kq + 3][n] = b.w;
    }
    __syncthreads();
#pragma unroll
    for (int kk = 0; kk < 16; ++kk) {
      float4 af = *(const float4*)&As[kk][ty << 2];
      float4 bf = *(const float4*)&Bs[kk][tx << 2];
      double ad[4] = {(double)af.x, (double)af.y, (double)af.z, (double)af.w};
      double bd[4] = {(double)bf.x, (double)bf.y, (double)bf.z, (double)bf.w};
#pragma unroll
      for (int i = 0; i < 4; ++i)
#pragma unroll
        for (int j = 0; j < 4; ++j)
          acc[i][j] = fma(ad[i], bd[j], acc[i][j]);
    }
    __syncthreads();
  }
#pragma unroll
  for (int i = 0; i < 4; ++i) {
    size_t coff = (size_t)(m0 + (ty << 2) + i) * N + n0 + (tx << 2);
    float4 o;
    o.x = (float)(acc[i][0] * alpha);
    o.y = (float)(acc[i][1] * alpha);
    o.z = (float)(acc[i][2] * alpha);
    o.w = (float)(acc[i][3] * alpha);
    *(float4*)(C + coff) = o;
  }
}

// ---------------------------------------------------------------------------
// RoPE in place + row L2 norms.
// Replicates the reference's f32 trig EXACTLY:
//   invf = f32(1 / f32(pow(10000, j/512)))   [f32-dtype-pinned in reference]
//   angf = f32(t) * invf                      [f32 multiply]
//   cos/sin = correctly-rounded f32 of angf   [f64 sincos of the f32 arg]
//   rotation in f32 with explicit no-contract ops (matches numpy elementwise)
// ---------------------------------------------------------------------------
__global__ void __launch_bounds__(256) rope_norm_kernel(float* __restrict__ bI,
                                                        float* __restrict__ bP,
                                                        float* __restrict__ nI,
                                                        float* __restrict__ nP)
{
  const int row = blockIdx.x;
  const int t = row & (T_LEN - 1);
  const int tid = threadIdx.x;
  __shared__ double redI[4], redP[4];
  double ssI = 0.0, ssP = 0.0;
  const size_t off = (size_t)row * D_DIM;
  for (int j = tid; j < 512; j += 256) {
    double e = (double)j * (1.0 / 512.0);          // exact, equals f32 value
    float pf = (float)pow(10000.0, e);             // == numpy's f32 powf (corr-rounded)
    float invf = 1.0f / pf;                        // f32 division
    float angf = (float)t * invf;                  // f32 multiply (the critical round)
    double s64, c64;
    sincos((double)angf, &s64, &c64);
    float c = (float)c64, s = (float)s64;          // correctly-rounded cosf/sinf(angf)

    float a1 = bI[off + j], a2 = bI[off + 512 + j];
    float o1 = __fsub_rn(__fmul_rn(a1, c), __fmul_rn(a2, s));
    float o2 = __fadd_rn(__fmul_rn(a1, s), __fmul_rn(a2, c));
    bI[off + j] = o1; bI[off + 512 + j] = o2;
    ssI += (double)o1 * o1 + (double)o2 * o2;

    float p1 = bP[off + j], p2 = bP[off + 512 + j];
    float q1 = __fsub_rn(__fmul_rn(p1, c), __fmul_rn(p2, s));
    float q2 = __fadd_rn(__fmul_rn(p1, s), __fmul_rn(p2, c));
    bP[off + j] = q1; bP[off + 512 + j] = q2;
    ssP += (double)q1 * q1 + (double)q2 * q2;
  }
#pragma unroll
  for (int o = 32; o >= 1; o >>= 1) { ssI += __shfl_xor(ssI, o); ssP += __shfl_xor(ssP, o); }
  if ((tid & 63) == 0) { redI[tid >> 6] = ssI; redP[tid >> 6] = ssP; }
  __syncthreads();
  if (tid == 0) {
    nI[row] = fmaxf((float)sqrt(redI[0] + redI[1] + redI[2] + redI[3]), 1e-12f);
    nP[row] = fmaxf((float)sqrt(redP[0] + redP[1] + redP[2] + redP[3]), 1e-12f);
  }
}

// ---------------------------------------------------------------------------
// palette (D x 256) -> palT (256 x D)
// ---------------------------------------------------------------------------
__global__ void transpose_pal(const float* __restrict__ pal, float* __restrict__ palT)
{
  int c = blockIdx.x;
  int d = blockIdx.y * 256 + threadIdx.x;
  palT[(size_t)c * D_DIM + d] = pal[(size_t)d * 256 + c];
}

// ---------------------------------------------------------------------------
// Top-15 per causal row. One wave per row. Descending; ties -> lower index.
// ---------------------------------------------------------------------------
__global__ void __launch_bounds__(256) topk_kernel(const float* __restrict__ S,
                                                   int* __restrict__ idx, int b)
{
  const int wave = threadIdx.x >> 6, lane = threadIdx.x & 63;
  const int t = blockIdx.x * 4 + wave;
  const float* rowp = S + (size_t)t * T_LEN;
  float v[32];
#pragma unroll
  for (int i = 0; i < 32; ++i) {
    int s = lane + (i << 6);
    v[i] = (s <= t) ? rowp[s] : -INFINITY;
  }
  float pv = INFINITY; int pidx = -1;
  int* outp = idx + ((size_t)b * T_LEN + t) * 16;
  for (int k = 0; k < KSEL; ++k) {
    float bv = -INFINITY; int bi = 0x7fffffff;
#pragma unroll
    for (int i = 0; i < 32; ++i) {
      int s = lane + (i << 6);
      float vv = v[i];
      bool elig = (vv < pv) || (vv == pv && s > pidx);
      if (elig && vv > bv) { bv = vv; bi = s; }
    }
#pragma unroll
    for (int o = 32; o >= 1; o >>= 1) {
      float ov = __shfl_xor(bv, o);
      int oi = __shfl_xor(bi, o);
      if (ov > bv || (ov == bv && oi < bi)) { bv = ov; bi = oi; }
    }
    pv = bv; pidx = bi;
    if (lane == 0) outp[k] = (bi == 0x7fffffff || bv == -INFINITY) ? 0 : bi;
  }
}

// ---------------------------------------------------------------------------
// Per-(b,t): gather + normalized gram + rel features + MLP + heads + softmax
// + bilinear palette blend -> V[b,t,:].
// ---------------------------------------------------------------------------
__global__ void __launch_bounds__(256) relmlp_kernel(
    const float* __restrict__ I, const float* __restrict__ P,
    const float* __restrict__ nI, const float* __restrict__ nP,
    const int* __restrict__ topk,
    const float* __restrict__ W1, const float* __restrict__ b1,
    const float* __restrict__ W2, const float* __restrict__ b2,
    const float* __restrict__ Wc, const float* __restrict__ bc,
    const float* __restrict__ Wm, const float* __restrict__ bm,
    const float* __restrict__ palT, float* __restrict__ V)
{
  const int row = blockIdx.x;
  const int t = row & (T_LEN - 1);
  const int base = row & ~(T_LEN - 1);
  const int nk = (t + 1 < KSEL) ? (t + 1) : KSEL;
  const int tid = threadIdx.x;

  __shared__ float vecS[16][516];
  __shared__ float gS[16][16];
  __shared__ float relS[KSEL][17];
  __shared__ float h1S[KSEL][HIDN];
  __shared__ float h2S[KSEL][HIDN];
  __shared__ float nrmS[16];
  __shared__ int   sidxS[16];
  __shared__ float mixS[KSEL], wS[KSEL], zxS[KSEL], zyS[KSEL];
  __shared__ float coefS[4 * KSEL];
  __shared__ int   cellS[4 * KSEL];

  if (tid < 16) {
    int s = t;
    if (tid >= 1) s = (tid <= nk) ? topk[(size_t)row * 16 + (tid - 1)] : 0;
    sidxS[tid] = s;
    nrmS[tid] = (tid == 0) ? nI[row] : nP[base + s];
  }
  __syncthreads();

  const int r = tid >> 4, c0 = tid & 15;
  const float* srcrow = (r == 0) ? (I + (size_t)row * D_DIM)
                                 : (P + ((size_t)base + sidxS[r]) * D_DIM);

  int pi = 0, pj = 0;
  {
    int p = tid;
    if (p < 136) {
      int i = 0;
      while (p >= 16 - i) { p -= 16 - i; ++i; }
      pi = i; pj = i + p;
    }
  }
  const bool pairOn = (tid < 136) && (pi <= nk) && (pj <= nk);
  float4 acc4 = make_float4(0.f, 0.f, 0.f, 0.f);

  for (int half = 0; half < 2; ++half) {
    if (half) __syncthreads();
    if (r <= nk) {
#pragma unroll
      for (int rep = 0; rep < 8; ++rep) {
        int q = c0 + 16 * rep;
        float4 v4 = *(const float4*)(srcrow + half * 512 + (q << 2));
        *(float4*)&vecS[r][q << 2] = v4;
      }
    }
    __syncthreads();
    if (pairOn) {
      const float4* va = (const float4*)&vecS[pi][0];
      const float4* vb = (const float4*)&vecS[pj][0];
#pragma unroll 4
      for (int q = 0; q < 128; ++q) {
        float4 a4 = va[q], b4 = vb[q];
        acc4.x = fmaf(a4.x, b4.x, acc4.x);
        acc4.y = fmaf(a4.y, b4.y, acc4.y);
        acc4.z = fmaf(a4.z, b4.z, acc4.z);
        acc4.w = fmaf(a4.w, b4.w, acc4.w);
      }
    }
  }
  if (tid < 136) {
    float g = 0.f;
    if (pairOn) {
      float acc = (acc4.x + acc4.y) + (acc4.z + acc4.w);
      g = acc / (nrmS[pi] * nrmS[pj]);
      g = fminf(fmaxf(g, -1.f), 1.f);
    }
    gS[pi][pj] = g;
    gS[pj][pi] = g;
  }
  __syncthreads();

  if (tid < KSEL * 17) {
    int k = tid / 17, f = tid % 17;
    float v = 0.f;
    if (k < nk) {
      if (f < KSEL)        v = (f < nk) ? gS[k + 1][f + 1] : 0.f;
      else if (f == KSEL)  v = gS[0][k + 1];
      else                 v = (float)(t - sidxS[k + 1]) * (1.0f / (float)T_LEN);
    }
    relS[k][f] = v;
  }
  __syncthreads();

  for (int o = tid; o < KSEL * HIDN; o += 256) {
    int k = o >> 6, m = o & 63;
    float a = b1[m];
#pragma unroll
    for (int f = 0; f < 17; ++f) a = fmaf(relS[k][f], W1[f * HIDN + m], a);
    h1S[k][m] = geluf(a);
  }
  __syncthreads();
  for (int o = tid; o < KSEL * HIDN; o += 256) {
    int k = o >> 6, m = o & 63;
    float a = b2[m];
#pragma unroll 8
    for (int n = 0; n < HIDN; ++n) a = fmaf(h1S[k][n], W2[n * HIDN + m], a);
    h2S[k][m] = geluf(a);
  }
  __syncthreads();
  if (tid < KSEL) {
    float a0 = 0.f, a1 = 0.f, am = 0.f;
#pragma unroll 8
    for (int n = 0; n < HIDN; ++n) {
      float h = h2S[tid][n];
      a0 = fmaf(h, Wc[n * 2 + 0], a0);
      a1 = fmaf(h, Wc[n * 2 + 1], a1);
      am = fmaf(h, Wm[n], am);
    }
    zxS[tid] = tanhf(a0 + bc[0]);
    zyS[tid] = tanhf(a1 + bc[1]);
    mixS[tid] = am + bm[0];
  }
  __syncthreads();
  if (tid == 0) {
    float mx = -INFINITY;
    for (int k = 0; k < nk; ++k) mx = fmaxf(mx, mixS[k]);
    float ssum = 0.f;
    for (int k = 0; k < nk; ++k) { float e = expf(mixS[k] - mx); wS[k] = e; ssum += e; }
    float inv = 1.f / ssum;
    for (int k = 0; k < nk; ++k) wS[k] *= inv;
  }
  __syncthreads();
  if (tid < KSEL) {
    int k = tid;
    if (k < nk) {
      float w = wS[k];
      float fx = fminf(fmaxf((zxS[k] + 1.f) * 0.5f * 15.f, 0.f), 15.f);
      float fy = fminf(fmaxf((zyS[k] + 1.f) * 0.5f * 15.f, 0.f), 15.f);
      int x0 = (int)floorf(fx); int x1i = (x0 + 1 < 15) ? x0 + 1 : 15;
      int y0 = (int)floorf(fy); int y1i = (y0 + 1 < 15) ? y0 + 1 : 15;
      float wx = fx - (float)x0, wy = fy - (float)y0;
      cellS[k * 4 + 0] = y0 * 16 + x0;   coefS[k * 4 + 0] = w * (1.f - wy) * (1.f - wx);
      cellS[k * 4 + 1] = y0 * 16 + x1i;  coefS[k * 4 + 1] = w * (1.f - wy) * wx;
      cellS[k * 4 + 2] = y1i * 16 + x0;  coefS[k * 4 + 2] = w * wy * (1.f - wx);
      cellS[k * 4 + 3] = y1i * 16 + x1i; coefS[k * 4 + 3] = w * wy * wx;
    } else {
      cellS[k * 4 + 0] = cellS[k * 4 + 1] = cellS[k * 4 + 2] = cellS[k * 4 + 3] = 0;
      coefS[k * 4 + 0] = coefS[k * 4 + 1] = coefS[k * 4 + 2] = coefS[k * 4 + 3] = 0.f;
    }
  }
  __syncthreads();
  const int nj = 4 * nk;
  for (int d = tid; d < D_DIM; d += 256) {
    float a = 0.f;
    for (int j = 0; j < nj; ++j)
      a = fmaf(coefS[j], palT[(size_t)cellS[j] * D_DIM + d], a);
    V[(size_t)row * D_DIM + d] = a;
  }
}

// ---------------------------------------------------------------------------
// Host launcher.
// ---------------------------------------------------------------------------
extern "C" void kernel_launch(void* const* d_in, const int* in_sizes, int n_in,
                              void* d_out, int out_size, void* d_ws, size_t ws_size,
                              hipStream_t stream)
{
  (void)in_sizes; (void)n_in; (void)out_size; (void)ws_size;
  const float* x   = (const float*)d_in[0];
  const float* Wi  = (const float*)d_in[1];
  const float* Wp  = (const float*)d_in[2];
  const float* pal = (const float*)d_in[3];
  const float* W1  = (const float*)d_in[4];
  const float* b1  = (const float*)d_in[5];
  const float* W2  = (const float*)d_in[6];
  const float* b2  = (const float*)d_in[7];
  const float* Wc  = (const float*)d_in[8];
  const float* bc  = (const float*)d_in[9];
  const float* Wm  = (const float*)d_in[10];
  const float* bm  = (const float*)d_in[11];
  const float* Wo  = (const float*)d_in[12];
  float* out = (float*)d_out;

  float* w = (float*)d_ws;
  float* palT = w;  w += (size_t)256 * D_DIM;
  float* I    = w;  w += (size_t)BATCH * T_LEN * D_DIM;
  float* P    = w;  w += (size_t)BATCH * T_LEN * D_DIM;
  float* Vb   = w;  w += (size_t)BATCH * T_LEN * D_DIM;
  float* Sb   = w;  w += (size_t)T_LEN * T_LEN;
  float* nIb  = w;  w += (size_t)BATCH * T_LEN;
  float* nPb  = w;  w += (size_t)BATCH * T_LEN;
  int*   idx  = (int*)w;

  const int MROWS = BATCH * T_LEN;  // 4096

  transpose_pal<<<dim3(256, 4), 256, 0, stream>>>(pal, palT);

  gemm64d<false, false><<<dim3(D_DIM / 64, MROWS / 64), 256, 0, stream>>>(
      x, Wi, I, MROWS, D_DIM, D_DIM, 1.0);
  gemm64d<false, false><<<dim3(D_DIM / 64, MROWS / 64), 256, 0, stream>>>(
      x, Wp, P, MROWS, D_DIM, D_DIM, 1.0);

  rope_norm_kernel<<<MROWS, 256, 0, stream>>>(I, P, nIb, nPb);

  for (int b = 0; b < BATCH; ++b) {
    gemm64d<true, true><<<dim3(T_LEN / 64, T_LEN / 64), 256, 0, stream>>>(
        I + (size_t)b * T_LEN * D_DIM, P + (size_t)b * T_LEN * D_DIM, Sb,
        T_LEN, T_LEN, D_DIM, 0.03125);
    topk_kernel<<<T_LEN / 4, 256, 0, stream>>>(Sb, idx, b);
  }

  relmlp_kernel<<<MROWS, 256, 0, stream>>>(I, P, nIb, nPb, idx,
                                           W1, b1, W2, b2, Wc, bc, Wm, bm,
                                           palT, Vb);

  gemm128<<<dim3(D_DIM / 128, MROWS / 128), 256, 0, stream>>>(
      Vb, Wo, out, MROWS, D_DIM, D_DIM, 1.0f);
}